// Round 13
// baseline (546.106 us; speedup 1.0000x reference)
//
#include <hip/hip_runtime.h>

#define NN 50000
#define NE 800000
#define E2 (NE + NN)   // edges + self loops
#define IN_DIM 128
#define SCAN_B 196     // ceil(NN/256)

typedef unsigned short u16;
typedef unsigned int u32;
typedef __attribute__((ext_vector_type(8))) short short8;
typedef __attribute__((ext_vector_type(4))) float f32x4;

__device__ inline u16 f2bf(float x) {
    u32 u = __float_as_uint(x);
    u32 r = (u + 0x7fff + ((u >> 16) & 1)) >> 16;   // RNE
    return (u16)r;
}
__device__ inline float bf2f(u16 h) { return __uint_as_float(((u32)h) << 16); }

// ---------------- fills ----------------
__global__ __launch_bounds__(256) void fill_i32(int* __restrict__ p, int v, int n) {
    int i = blockIdx.x * 256 + threadIdx.x;
    if (i < n) p[i] = v;
}

// ---------------- CSR build ----------------
__global__ __launch_bounds__(256) void hist_dst(const int* __restrict__ ei, int* __restrict__ deg) {
    int e = blockIdx.x * 256 + threadIdx.x;
    if (e < NE) atomicAdd(&deg[ei[NE + e]], 1);
}

__global__ __launch_bounds__(256) void block_sums(const int* __restrict__ deg, int* __restrict__ bsum) {
    int b = blockIdx.x;
    int i = b * 256 + threadIdx.x;
    int v = (i < NN) ? deg[i] : 0;
#pragma unroll
    for (int off = 32; off; off >>= 1) v += __shfl_down(v, off);
    __shared__ int ws[4];
    if ((threadIdx.x & 63) == 0) ws[threadIdx.x >> 6] = v;
    __syncthreads();
    if (threadIdx.x == 0) bsum[b] = ws[0] + ws[1] + ws[2] + ws[3];
}

__global__ __launch_bounds__(256) void scan_bsums(const int* __restrict__ bsum, int* __restrict__ boff) {
    __shared__ int s[256];
    int t = threadIdx.x;
    int v = (t < SCAN_B) ? bsum[t] : 0;
    s[t] = v;
    __syncthreads();
    for (int off = 1; off < 256; off <<= 1) {
        int u = (t >= off) ? s[t - off] : 0;
        __syncthreads();
        s[t] += u;
        __syncthreads();
    }
    if (t < SCAN_B) boff[t] = s[t] - v;
}

__global__ __launch_bounds__(256) void scan_final(const int* __restrict__ deg,
                                                  const int* __restrict__ boff,
                                                  int* __restrict__ rowptr,
                                                  int* __restrict__ cursor) {
    int b = blockIdx.x;
    int t = threadIdx.x;
    int i = b * 256 + t;
    int v = (i < NN) ? deg[i] : 0;
    __shared__ int s[256];
    s[t] = v;
    __syncthreads();
    for (int off = 1; off < 256; off <<= 1) {
        int u = (t >= off) ? s[t - off] : 0;
        __syncthreads();
        s[t] += u;
        __syncthreads();
    }
    int excl = s[t] - v + boff[b];
    if (i < NN) { rowptr[i] = excl; cursor[i] = excl; }
    if (i == NN - 1) rowptr[NN] = excl + v;
}

__global__ __launch_bounds__(256) void scatter_csr(const int* __restrict__ ei,
                                                   int* __restrict__ cursor,
                                                   int* __restrict__ csr_src) {
    int e = blockIdx.x * 256 + threadIdx.x;
    if (e >= E2) return;
    int s, d;
    if (e < NE) { s = ei[e]; d = ei[NE + e]; } else { s = d = e - NE; }
    int pos = atomicAdd(&cursor[d], 1);
    csr_src[pos] = s;
}

// ---------------- split-bf16 converters ----------------
__global__ __launch_bounds__(256) void xconv(const float* __restrict__ X,
                                             u16* __restrict__ Xh, u16* __restrict__ Xl,
                                             int total4) {
    int i = blockIdx.x * 256 + threadIdx.x;
    if (i >= total4) return;
    float4 v = reinterpret_cast<const float4*>(X)[i];
    ushort4 h, l;
    h.x = f2bf(v.x); l.x = f2bf(v.x - bf2f(h.x));
    h.y = f2bf(v.y); l.y = f2bf(v.y - bf2f(h.y));
    h.z = f2bf(v.z); l.z = f2bf(v.z - bf2f(h.z));
    h.w = f2bf(v.w); l.w = f2bf(v.w - bf2f(h.w));
    reinterpret_cast<ushort4*>(Xh)[i] = h;
    reinterpret_cast<ushort4*>(Xl)[i] = l;
}

__global__ __launch_bounds__(256) void wconv(const float* __restrict__ W,
                                             u16* __restrict__ Wh, u16* __restrict__ Wl,
                                             int K, int N) {
    int idx = blockIdx.x * 256 + threadIdx.x;
    if (idx >= K * N) return;
    int k = idx / N, n = idx - k * N;
    float w = W[idx];
    u16 hi = f2bf(w);
    Wh[(size_t)n * K + k] = hi;
    Wl[(size_t)n * K + k] = f2bf(w - bf2f(hi));
}

// ---------------- split-bf16 MFMA GEMM (LDS-FREE: A and B direct from global) ----------------
// Rationale: LDS-staged A was read-BW-bound (8 waves x 8KB = 64KB/CU-step ~ 770cy
// at 85 B/cy vs MFMA 466cy). Direct A loads: 16 rows x 64B contiguous per frag
// (fully-consumed lines); wn-pair duplication absorbed by L1/L2. Zero barriers ->
// compiler pipelines loads across MFMAs freely.
// FES epilogue: BN=128 (H=4) wave owns one head; BN=64 (H=1) cross-wave LDS reduce.
template<int BN, int KK, bool FES>
__global__ __launch_bounds__(256) void gemm_mfma(const u16* __restrict__ Ah,
                                                 const u16* __restrict__ Al,
                                                 const u16* __restrict__ Wh,
                                                 const u16* __restrict__ Wl,
                                                 float* __restrict__ C,
                                                 int M, int N,
                                                 const float* __restrict__ as_,
                                                 const float* __restrict__ ad_,
                                                 float* __restrict__ es,
                                                 float* __restrict__ ed) {
    const int BM = 128;
    const int FRN = BN / 32;
    int tid = threadIdx.x;
    int lane = tid & 63, wid = tid >> 6;
    int wm = wid >> 1, wn = wid & 1;
    int row0 = blockIdx.x * BM, col0 = blockIdx.y * BN;
    int l15 = lane & 15, lg = lane >> 4;

    // per-fragment base pointers (row clamped to M-1: harmless dup, avoids OOB)
    const u16* aph[4];
    const u16* apl[4];
#pragma unroll
    for (int i = 0; i < 4; ++i) {
        int r = row0 + wm * 64 + i * 16 + l15;
        if (r > M - 1) r = M - 1;
        aph[i] = Ah + (size_t)r * KK + lg * 8;
        apl[i] = Al + (size_t)r * KK + lg * 8;
    }
    const u16* bph[FRN];
    const u16* bpl[FRN];
#pragma unroll
    for (int j = 0; j < FRN; ++j) {
        int gc = col0 + wn * (BN / 2) + j * 16 + l15;
        bph[j] = Wh + (size_t)gc * KK + lg * 8;
        bpl[j] = Wl + (size_t)gc * KK + lg * 8;
    }

    f32x4 acc[4][FRN];
#pragma unroll
    for (int i = 0; i < 4; ++i)
#pragma unroll
        for (int j = 0; j < FRN; ++j) acc[i][j] = (f32x4){0.f, 0.f, 0.f, 0.f};

#pragma unroll 2
    for (int ko = 0; ko < KK; ko += 32) {
        short8 ah[4], al[4], bh[FRN], bl[FRN];
#pragma unroll
        for (int i = 0; i < 4; ++i) {
            ah[i] = *reinterpret_cast<const short8*>(aph[i] + ko);
            al[i] = *reinterpret_cast<const short8*>(apl[i] + ko);
        }
#pragma unroll
        for (int j = 0; j < FRN; ++j) {
            bh[j] = *reinterpret_cast<const short8*>(bph[j] + ko);
            bl[j] = *reinterpret_cast<const short8*>(bpl[j] + ko);
        }
#pragma unroll
        for (int i = 0; i < 4; ++i)
#pragma unroll
            for (int j = 0; j < FRN; ++j) {
                acc[i][j] = __builtin_amdgcn_mfma_f32_16x16x32_bf16(ah[i], bh[j], acc[i][j], 0, 0, 0);
                acc[i][j] = __builtin_amdgcn_mfma_f32_16x16x32_bf16(ah[i], bl[j], acc[i][j], 0, 0, 0);
                acc[i][j] = __builtin_amdgcn_mfma_f32_16x16x32_bf16(al[i], bh[j], acc[i][j], 0, 0, 0);
            }
    }
    // C store
#pragma unroll
    for (int i = 0; i < 4; ++i)
#pragma unroll
        for (int rr = 0; rr < 4; ++rr) {
            int gr = row0 + wm * 64 + i * 16 + lg * 4 + rr;
            if (gr < M) {
#pragma unroll
                for (int j = 0; j < FRN; ++j)
                    C[(size_t)gr * N + col0 + wn * (BN / 2) + j * 16 + l15] = acc[i][j][rr];
            }
        }
    if (FES) {
        if constexpr (BN == 128) {
            int head = (col0 + wn * (BN / 2)) >> 6;
            float asv[FRN], adv[FRN];
#pragma unroll
            for (int j = 0; j < FRN; ++j) {
                asv[j] = as_[head * 64 + j * 16 + l15];
                adv[j] = ad_[head * 64 + j * 16 + l15];
            }
#pragma unroll
            for (int i = 0; i < 4; ++i)
#pragma unroll
                for (int rr = 0; rr < 4; ++rr) {
                    float vs = 0.f, vd = 0.f;
#pragma unroll
                    for (int j = 0; j < FRN; ++j) {
                        vs += acc[i][j][rr] * asv[j];
                        vd += acc[i][j][rr] * adv[j];
                    }
#pragma unroll
                    for (int off = 1; off < 16; off <<= 1) {
                        vs += __shfl_xor(vs, off);
                        vd += __shfl_xor(vd, off);
                    }
                    int gr = row0 + wm * 64 + i * 16 + lg * 4 + rr;
                    if (l15 == 0 && gr < M) {
                        es[gr * 4 + head] = vs;
                        ed[gr * 4 + head] = vd;
                    }
                }
        } else {
            // H=1: wave covers 32 of 64 cols; cross-wave (wn) reduce via LDS
            __shared__ float esp[2][BM], edp[2][BM];
            float asv[FRN], adv[FRN];
#pragma unroll
            for (int j = 0; j < FRN; ++j) {
                asv[j] = as_[wn * (BN / 2) + j * 16 + l15];
                adv[j] = ad_[wn * (BN / 2) + j * 16 + l15];
            }
#pragma unroll
            for (int i = 0; i < 4; ++i)
#pragma unroll
                for (int rr = 0; rr < 4; ++rr) {
                    float vs = 0.f, vd = 0.f;
#pragma unroll
                    for (int j = 0; j < FRN; ++j) {
                        vs += acc[i][j][rr] * asv[j];
                        vd += acc[i][j][rr] * adv[j];
                    }
#pragma unroll
                    for (int off = 1; off < 16; off <<= 1) {
                        vs += __shfl_xor(vs, off);
                        vd += __shfl_xor(vd, off);
                    }
                    int rl = wm * 64 + i * 16 + lg * 4 + rr;
                    if (l15 == 0) { esp[wn][rl] = vs; edp[wn][rl] = vd; }
                }
            __syncthreads();
            if (tid < BM) {
                int gr = row0 + tid;
                if (gr < M) {
                    es[gr] = esp[0][tid] + esp[1][tid];
                    ed[gr] = edp[0][tid] + edp[1][tid];
                }
            }
        }
    }
}

// ---------------- FUSED softmax + aggregate + norm + bias + relu ----------------
// Phase B: simple 8x-unrolled loop + serial tail (round-6 structure, 40 VGPR —
// explicit pipelining/predication both regressed: R7 −6us/occ 38%, R11 −4us/occ 36%).
// FC=false: emit split-bf16 pair. FC=true: fused 64->10 classifier -> d_out.
template<int D, int H, bool FC>
__global__ __launch_bounds__(256) void agg_fused(const int* __restrict__ rowptr,
                                                 const int* __restrict__ csr_src,
                                                 const float* __restrict__ es,
                                                 const float* __restrict__ ed,
                                                 const float* __restrict__ h,
                                                 const float* __restrict__ b,
                                                 u16* __restrict__ Oh,
                                                 u16* __restrict__ Ol,
                                                 const float* __restrict__ fcW,
                                                 const float* __restrict__ fcb,
                                                 float* __restrict__ out) {
    const int TPN = D / 4;
    const int NPB = 256 / TPN;
    const int logH = (H == 4) ? 2 : 0;
    int tid = threadIdx.x;
    int n = blockIdx.x * NPB + tid / TPN;
    if (n >= NN) return;
    int gl = tid % TPN;
    int start = rowptr[n], end = rowptr[n + 1];

    // ---- phase A: per-head max over edges (edge-parallel) ----
    int headA = gl & (H - 1);
    const int JP = TPN >> logH;
    float edvA = ed[n * H + headA];
    float m = -1e30f;
    for (int i = start + (gl >> logH); i < end; i += JP) {
        int src = csr_src[i];
        float v = es[src * H + headA] + edvA;
        v = v > 0.f ? v : 0.2f * v;
        m = fmaxf(m, v);
    }
#pragma unroll
    for (int off = H; off < TPN; off <<= 1)
        m = fmaxf(m, __shfl_xor(m, off));

    // ---- phase B: serial edge loop, p inline, gather h ----
    int f0 = gl * 4;
    int hb = f0 >> 6;
    float mB;
    if (D == 256) mB = __shfl(m, hb);
    else          mB = m;
    float edv = ed[n * H + hb];
    float sump = 0.f;
    float4 acc = make_float4(0.f, 0.f, 0.f, 0.f);
    int i = start;
    for (; i + 8 <= end; i += 8) {
        int s0 = csr_src[i + 0], s1 = csr_src[i + 1], s2 = csr_src[i + 2], s3 = csr_src[i + 3];
        int s4 = csr_src[i + 4], s5 = csr_src[i + 5], s6 = csr_src[i + 6], s7 = csr_src[i + 7];
        float v0 = es[s0 * H + hb] + edv, v1 = es[s1 * H + hb] + edv;
        float v2 = es[s2 * H + hb] + edv, v3 = es[s3 * H + hb] + edv;
        float v4 = es[s4 * H + hb] + edv, v5 = es[s5 * H + hb] + edv;
        float v6 = es[s6 * H + hb] + edv, v7 = es[s7 * H + hb] + edv;
        v0 = v0 > 0.f ? v0 : 0.2f * v0; v1 = v1 > 0.f ? v1 : 0.2f * v1;
        v2 = v2 > 0.f ? v2 : 0.2f * v2; v3 = v3 > 0.f ? v3 : 0.2f * v3;
        v4 = v4 > 0.f ? v4 : 0.2f * v4; v5 = v5 > 0.f ? v5 : 0.2f * v5;
        v6 = v6 > 0.f ? v6 : 0.2f * v6; v7 = v7 > 0.f ? v7 : 0.2f * v7;
        float p0 = __expf(v0 - mB), p1 = __expf(v1 - mB);
        float p2 = __expf(v2 - mB), p3 = __expf(v3 - mB);
        float p4 = __expf(v4 - mB), p5 = __expf(v5 - mB);
        float p6 = __expf(v6 - mB), p7 = __expf(v7 - mB);
        float4 h0 = *reinterpret_cast<const float4*>(h + (size_t)s0 * D + f0);
        float4 h1 = *reinterpret_cast<const float4*>(h + (size_t)s1 * D + f0);
        float4 h2 = *reinterpret_cast<const float4*>(h + (size_t)s2 * D + f0);
        float4 h3 = *reinterpret_cast<const float4*>(h + (size_t)s3 * D + f0);
        float4 h4 = *reinterpret_cast<const float4*>(h + (size_t)s4 * D + f0);
        float4 h5 = *reinterpret_cast<const float4*>(h + (size_t)s5 * D + f0);
        float4 h6 = *reinterpret_cast<const float4*>(h + (size_t)s6 * D + f0);
        float4 h7 = *reinterpret_cast<const float4*>(h + (size_t)s7 * D + f0);
        acc.x += p0 * h0.x + p1 * h1.x + p2 * h2.x + p3 * h3.x
               + p4 * h4.x + p5 * h5.x + p6 * h6.x + p7 * h7.x;
        acc.y += p0 * h0.y + p1 * h1.y + p2 * h2.y + p3 * h3.y
               + p4 * h4.y + p5 * h5.y + p6 * h6.y + p7 * h7.y;
        acc.z += p0 * h0.z + p1 * h1.z + p2 * h2.z + p3 * h3.z
               + p4 * h4.z + p5 * h5.z + p6 * h6.z + p7 * h7.z;
        acc.w += p0 * h0.w + p1 * h1.w + p2 * h2.w + p3 * h3.w
               + p4 * h4.w + p5 * h5.w + p6 * h6.w + p7 * h7.w;
        sump += p0 + p1 + p2 + p3 + p4 + p5 + p6 + p7;
    }
    for (; i < end; ++i) {
        int s0 = csr_src[i];
        float v = es[s0 * H + hb] + edv;
        v = v > 0.f ? v : 0.2f * v;
        float p = __expf(v - mB);
        float4 h0 = *reinterpret_cast<const float4*>(h + (size_t)s0 * D + f0);
        acc.x += p * h0.x; acc.y += p * h0.y; acc.z += p * h0.z; acc.w += p * h0.w;
        sump += p;
    }
    float inv = 1.f / (sump + 1e-16f);
    float4 bb = *reinterpret_cast<const float4*>(b + f0);
    float4 o;
    o.x = acc.x * inv + bb.x; o.y = acc.y * inv + bb.y;
    o.z = acc.z * inv + bb.z; o.w = acc.w * inv + bb.w;
    o.x = o.x > 0.f ? o.x : 0.f; o.y = o.y > 0.f ? o.y : 0.f;
    o.z = o.z > 0.f ? o.z : 0.f; o.w = o.w > 0.f ? o.w : 0.f;
    if (!FC) {
        ushort4 hv, lv;
        hv.x = f2bf(o.x); lv.x = f2bf(o.x - bf2f(hv.x));
        hv.y = f2bf(o.y); lv.y = f2bf(o.y - bf2f(hv.y));
        hv.z = f2bf(o.z); lv.z = f2bf(o.z - bf2f(hv.z));
        hv.w = f2bf(o.w); lv.w = f2bf(o.w - bf2f(hv.w));
        *reinterpret_cast<ushort4*>(Oh + (size_t)n * D + f0) = hv;
        *reinterpret_cast<ushort4*>(Ol + (size_t)n * D + f0) = lv;
    } else {
        // fused 64->10 classifier: lane holds features f0..f0+3
        float pj[10];
#pragma unroll
        for (int j = 0; j < 10; ++j)
            pj[j] = o.x * fcW[(f0 + 0) * 10 + j] + o.y * fcW[(f0 + 1) * 10 + j]
                  + o.z * fcW[(f0 + 2) * 10 + j] + o.w * fcW[(f0 + 3) * 10 + j];
#pragma unroll
        for (int off = 1; off < 16; off <<= 1)
#pragma unroll
            for (int j = 0; j < 10; ++j)
                pj[j] += __shfl_xor(pj[j], off);
        if (gl < 10) {
            float r = 0.f;                 // static-index select (avoid scratch)
#pragma unroll
            for (int j = 0; j < 10; ++j) if (gl == j) r = pj[j];
            out[n * 10 + gl] = r + fcb[gl];
        }
    }
}

extern "C" void kernel_launch(void* const* d_in, const int* in_sizes, int n_in,
                              void* d_out, int out_size, void* d_ws, size_t ws_size,
                              hipStream_t stream) {
    const float* x   = (const float*)d_in[0];
    const int*   ei  = (const int*)d_in[1];
    const float* W1  = (const float*)d_in[2];
    const float* a1s = (const float*)d_in[3];
    const float* a1d = (const float*)d_in[4];
    const float* b1  = (const float*)d_in[5];
    const float* W2  = (const float*)d_in[6];
    const float* a2s = (const float*)d_in[7];
    const float* a2d = (const float*)d_in[8];
    const float* b2  = (const float*)d_in[9];
    const float* W3  = (const float*)d_in[10];
    const float* a3s = (const float*)d_in[11];
    const float* a3d = (const float*)d_in[12];
    const float* b3  = (const float*)d_in[13];
    const float* fcW = (const float*)d_in[14];
    const float* fcb = (const float*)d_in[15];
    float* out = (float*)d_out;

    // ---- workspace layout ----
    char* wp = (char*)d_ws;
    float* h   = (float*)wp;  wp += (size_t)NN * 256 * 4;     // GEMM output, f32
    u16* Ph    = (u16*)wp;    wp += (size_t)NN * 256 * 2;     // activation hi
    u16* Pl    = (u16*)wp;    wp += (size_t)NN * 256 * 2;     // activation lo
    u16* Xh    = (u16*)wp;    wp += (size_t)NN * 128 * 2;     // x hi
    u16* Xl    = (u16*)wp;    wp += (size_t)NN * 128 * 2;     // x lo
    float* ES  = (float*)wp;  wp += (size_t)NN * 4 * 4;
    float* ED  = (float*)wp;  wp += (size_t)NN * 4 * 4;
    u16* Wth   = (u16*)wp;    wp += 256 * 256 * 2;
    u16* Wtl   = (u16*)wp;    wp += 256 * 256 * 2;
    int* rowptr = (int*)wp;   wp += (NN + 1) * 4;
    int* csrsrc = (int*)wp;   wp += (size_t)E2 * 4;
    int* deg    = (int*)wp;   wp += NN * 4;
    int* bsum   = (int*)wp;   wp += 256 * 4;
    int* boff   = (int*)wp;   wp += 256 * 4;
    int* cursor = (int*)((char*)d_ws + (size_t)NN * 256 * 4);  // alias Ph (pre-layer only)

    // ---- build CSR ----
    fill_i32<<<(NN + 255) / 256, 256, 0, stream>>>(deg, 1, NN);
    hist_dst<<<(NE + 255) / 256, 256, 0, stream>>>(ei, deg);
    block_sums<<<SCAN_B, 256, 0, stream>>>(deg, bsum);
    scan_bsums<<<1, 256, 0, stream>>>(bsum, boff);
    scan_final<<<SCAN_B, 256, 0, stream>>>(deg, boff, rowptr, cursor);
    scatter_csr<<<(E2 + 255) / 256, 256, 0, stream>>>(ei, cursor, csrsrc);

    // ---- split input x ----
    xconv<<<(NN * IN_DIM / 4 + 255) / 256, 256, 0, stream>>>(x, Xh, Xl, NN * IN_DIM / 4);

    const int MT = (NN + 127) / 128;

    // ======== layer 1: K=128, D=256, H=4 (escore fused into GEMM) ========
    wconv<<<(IN_DIM * 256 + 255) / 256, 256, 0, stream>>>(W1, Wth, Wtl, IN_DIM, 256);
    gemm_mfma<128, 128, true><<<dim3(MT, 2), 256, 0, stream>>>(Xh, Xl, Wth, Wtl, h, NN, 256,
                                                               a1s, a1d, ES, ED);
    agg_fused<256, 4, false><<<(NN + 3) / 4, 256, 0, stream>>>(rowptr, csrsrc, ES, ED, h, b1,
                                                               Ph, Pl, nullptr, nullptr, nullptr);

    // ======== layer 2: K=256, D=256, H=4 (escore fused into GEMM) ========
    wconv<<<(256 * 256 + 255) / 256, 256, 0, stream>>>(W2, Wth, Wtl, 256, 256);
    gemm_mfma<128, 256, true><<<dim3(MT, 2), 256, 0, stream>>>(Ph, Pl, Wth, Wtl, h, NN, 256,
                                                               a2s, a2d, ES, ED);
    agg_fused<256, 4, false><<<(NN + 3) / 4, 256, 0, stream>>>(rowptr, csrsrc, ES, ED, h, b2,
                                                               Ph, Pl, nullptr, nullptr, nullptr);

    // ======== layer 3: K=256, D=64, H=1 (escore fused into GEMM, fc fused into agg) ========
    wconv<<<(256 * 64 + 255) / 256, 256, 0, stream>>>(W3, Wth, Wtl, 256, 64);
    gemm_mfma<64, 256, true><<<dim3(MT, 1), 256, 0, stream>>>(Ph, Pl, Wth, Wtl, h, NN, 64,
                                                              a3s, a3d, ES, ED);
    agg_fused<64, 1, true><<<(NN + 15) / 16, 256, 0, stream>>>(rowptr, csrsrc, ES, ED, h, b3,
                                                               nullptr, nullptr, fcW, fcb, out);
}

// Round 14
// 520.915 us; speedup vs baseline: 1.0484x; 1.0484x over previous
//
#include <hip/hip_runtime.h>

#define NN 50000
#define NE 800000
#define E2 (NE + NN)   // edges + self loops
#define IN_DIM 128
#define SCAN_B 196     // ceil(NN/256)

typedef unsigned short u16;
typedef unsigned int u32;
typedef __attribute__((ext_vector_type(8))) short short8;
typedef __attribute__((ext_vector_type(4))) float f32x4;

__device__ inline u16 f2bf(float x) {
    u32 u = __float_as_uint(x);
    u32 r = (u + 0x7fff + ((u >> 16) & 1)) >> 16;   // RNE
    return (u16)r;
}
__device__ inline float bf2f(u16 h) { return __uint_as_float(((u32)h) << 16); }

// ---------------- fills ----------------
__global__ __launch_bounds__(256) void fill_i32(int* __restrict__ p, int v, int n) {
    int i = blockIdx.x * 256 + threadIdx.x;
    if (i < n) p[i] = v;
}

// ---------------- CSR build ----------------
__global__ __launch_bounds__(256) void hist_dst(const int* __restrict__ ei, int* __restrict__ deg) {
    int e = blockIdx.x * 256 + threadIdx.x;
    if (e < NE) atomicAdd(&deg[ei[NE + e]], 1);
}

__global__ __launch_bounds__(256) void block_sums(const int* __restrict__ deg, int* __restrict__ bsum) {
    int b = blockIdx.x;
    int i = b * 256 + threadIdx.x;
    int v = (i < NN) ? deg[i] : 0;
#pragma unroll
    for (int off = 32; off; off >>= 1) v += __shfl_down(v, off);
    __shared__ int ws[4];
    if ((threadIdx.x & 63) == 0) ws[threadIdx.x >> 6] = v;
    __syncthreads();
    if (threadIdx.x == 0) bsum[b] = ws[0] + ws[1] + ws[2] + ws[3];
}

__global__ __launch_bounds__(256) void scan_bsums(const int* __restrict__ bsum, int* __restrict__ boff) {
    __shared__ int s[256];
    int t = threadIdx.x;
    int v = (t < SCAN_B) ? bsum[t] : 0;
    s[t] = v;
    __syncthreads();
    for (int off = 1; off < 256; off <<= 1) {
        int u = (t >= off) ? s[t - off] : 0;
        __syncthreads();
        s[t] += u;
        __syncthreads();
    }
    if (t < SCAN_B) boff[t] = s[t] - v;
}

__global__ __launch_bounds__(256) void scan_final(const int* __restrict__ deg,
                                                  const int* __restrict__ boff,
                                                  int* __restrict__ rowptr,
                                                  int* __restrict__ cursor) {
    int b = blockIdx.x;
    int t = threadIdx.x;
    int i = b * 256 + t;
    int v = (i < NN) ? deg[i] : 0;
    __shared__ int s[256];
    s[t] = v;
    __syncthreads();
    for (int off = 1; off < 256; off <<= 1) {
        int u = (t >= off) ? s[t - off] : 0;
        __syncthreads();
        s[t] += u;
        __syncthreads();
    }
    int excl = s[t] - v + boff[b];
    if (i < NN) { rowptr[i] = excl; cursor[i] = excl; }
    if (i == NN - 1) rowptr[NN] = excl + v;
}

__global__ __launch_bounds__(256) void scatter_csr(const int* __restrict__ ei,
                                                   int* __restrict__ cursor,
                                                   int* __restrict__ csr_src) {
    int e = blockIdx.x * 256 + threadIdx.x;
    if (e >= E2) return;
    int s, d;
    if (e < NE) { s = ei[e]; d = ei[NE + e]; } else { s = d = e - NE; }
    int pos = atomicAdd(&cursor[d], 1);
    csr_src[pos] = s;
}

// ---------------- split-bf16 converters ----------------
__global__ __launch_bounds__(256) void xconv(const float* __restrict__ X,
                                             u16* __restrict__ Xh, u16* __restrict__ Xl,
                                             int total4) {
    int i = blockIdx.x * 256 + threadIdx.x;
    if (i >= total4) return;
    float4 v = reinterpret_cast<const float4*>(X)[i];
    ushort4 h, l;
    h.x = f2bf(v.x); l.x = f2bf(v.x - bf2f(h.x));
    h.y = f2bf(v.y); l.y = f2bf(v.y - bf2f(h.y));
    h.z = f2bf(v.z); l.z = f2bf(v.z - bf2f(h.z));
    h.w = f2bf(v.w); l.w = f2bf(v.w - bf2f(h.w));
    reinterpret_cast<ushort4*>(Xh)[i] = h;
    reinterpret_cast<ushort4*>(Xl)[i] = l;
}

__global__ __launch_bounds__(256) void wconv(const float* __restrict__ W,
                                             u16* __restrict__ Wh, u16* __restrict__ Wl,
                                             int K, int N) {
    int idx = blockIdx.x * 256 + threadIdx.x;
    if (idx >= K * N) return;
    int k = idx / N, n = idx - k * N;
    float w = W[idx];
    u16 hi = f2bf(w);
    Wh[(size_t)n * K + k] = hi;
    Wl[(size_t)n * K + k] = f2bf(w - bf2f(hi));
}

// ---------------- split-bf16 MFMA GEMM (double-buffered A, 1 barrier/K-step) ----------------
// R12 structure (local optimum: R8 LDS-heavier flat, R13 LDS-free −13.5us).
// A staged via 2x LDS buffers w/ 2-step register prefetch; B direct from global (L2-hot).
// FES epilogue: BN=128 (H=4) wave owns one head; BN=64 (H=1) cross-wave LDS reduce.
template<int BN, int KK, bool FES>
__global__ __launch_bounds__(256) void gemm_mfma(const u16* __restrict__ Ah,
                                                 const u16* __restrict__ Al,
                                                 const u16* __restrict__ Wh,
                                                 const u16* __restrict__ Wl,
                                                 float* __restrict__ C,
                                                 int M, int N,
                                                 const float* __restrict__ as_,
                                                 const float* __restrict__ ad_,
                                                 float* __restrict__ es,
                                                 float* __restrict__ ed) {
    const int BM = 128, BK = 32, LDT = BK + 8;
    __shared__ u16 Ahs[2][BM][LDT], Als[2][BM][LDT];   // 40 KB
    const int FRN = BN / 32;
    int tid = threadIdx.x;
    int lane = tid & 63, wid = tid >> 6;
    int wm = wid >> 1, wn = wid & 1;
    int row0 = blockIdx.x * BM, col0 = blockIdx.y * BN;
    int l15 = lane & 15, lg = lane >> 4;

    int c0 = tid * 2;
    int r_a = c0 >> 2, sub_a0 = (c0 & 3) * 8, sub_a1 = ((c0 + 1) & 3) * 8;
    int gr_a = row0 + r_a;

    uint4 avh[2], avl[2];
    auto loadA = [&](int ko) {
        if (gr_a < M) {
            avh[0] = *reinterpret_cast<const uint4*>(Ah + (size_t)gr_a * KK + ko + sub_a0);
            avl[0] = *reinterpret_cast<const uint4*>(Al + (size_t)gr_a * KK + ko + sub_a0);
            avh[1] = *reinterpret_cast<const uint4*>(Ah + (size_t)gr_a * KK + ko + sub_a1);
            avl[1] = *reinterpret_cast<const uint4*>(Al + (size_t)gr_a * KK + ko + sub_a1);
        } else {
            avh[0] = avh[1] = avl[0] = avl[1] = make_uint4(0, 0, 0, 0);
        }
    };
    auto writeA = [&](int p) {
        *reinterpret_cast<uint4*>(&Ahs[p][r_a][sub_a0]) = avh[0];
        *reinterpret_cast<uint4*>(&Als[p][r_a][sub_a0]) = avl[0];
        *reinterpret_cast<uint4*>(&Ahs[p][r_a][sub_a1]) = avh[1];
        *reinterpret_cast<uint4*>(&Als[p][r_a][sub_a1]) = avl[1];
    };

    f32x4 acc[4][FRN];
#pragma unroll
    for (int i = 0; i < 4; ++i)
#pragma unroll
        for (int j = 0; j < FRN; ++j) acc[i][j] = (f32x4){0.f, 0.f, 0.f, 0.f};

    loadA(0);
    writeA(0);
    loadA(BK);
    __syncthreads();

    for (int ko = 0; ko < KK; ko += BK) {
        int p = (ko >> 5) & 1;
        if (ko + BK < KK) {
            writeA(p ^ 1);
            if (ko + 2 * BK < KK) loadA(ko + 2 * BK);
        }
        short8 bh[FRN], bl[FRN];
#pragma unroll
        for (int j = 0; j < FRN; ++j) {
            int gc = col0 + wn * (BN / 2) + j * 16 + l15;
            bh[j] = *reinterpret_cast<const short8*>(Wh + (size_t)gc * KK + ko + lg * 8);
            bl[j] = *reinterpret_cast<const short8*>(Wl + (size_t)gc * KK + ko + lg * 8);
        }
        short8 ah[4], al[4];
#pragma unroll
        for (int i = 0; i < 4; ++i) {
            int r = wm * 64 + i * 16 + l15;
            ah[i] = *reinterpret_cast<const short8*>(&Ahs[p][r][lg * 8]);
            al[i] = *reinterpret_cast<const short8*>(&Als[p][r][lg * 8]);
        }
#pragma unroll
        for (int i = 0; i < 4; ++i)
#pragma unroll
            for (int j = 0; j < FRN; ++j) {
                acc[i][j] = __builtin_amdgcn_mfma_f32_16x16x32_bf16(ah[i], bh[j], acc[i][j], 0, 0, 0);
                acc[i][j] = __builtin_amdgcn_mfma_f32_16x16x32_bf16(ah[i], bl[j], acc[i][j], 0, 0, 0);
                acc[i][j] = __builtin_amdgcn_mfma_f32_16x16x32_bf16(al[i], bh[j], acc[i][j], 0, 0, 0);
            }
        __syncthreads();
    }
    // C store
#pragma unroll
    for (int i = 0; i < 4; ++i)
#pragma unroll
        for (int rr = 0; rr < 4; ++rr) {
            int gr = row0 + wm * 64 + i * 16 + lg * 4 + rr;
            if (gr < M) {
#pragma unroll
                for (int j = 0; j < FRN; ++j)
                    C[(size_t)gr * N + col0 + wn * (BN / 2) + j * 16 + l15] = acc[i][j][rr];
            }
        }
    if (FES) {
        if constexpr (BN == 128) {
            int head = (col0 + wn * (BN / 2)) >> 6;
            float asv[FRN], adv[FRN];
#pragma unroll
            for (int j = 0; j < FRN; ++j) {
                asv[j] = as_[head * 64 + j * 16 + l15];
                adv[j] = ad_[head * 64 + j * 16 + l15];
            }
#pragma unroll
            for (int i = 0; i < 4; ++i)
#pragma unroll
                for (int rr = 0; rr < 4; ++rr) {
                    float vs = 0.f, vd = 0.f;
#pragma unroll
                    for (int j = 0; j < FRN; ++j) {
                        vs += acc[i][j][rr] * asv[j];
                        vd += acc[i][j][rr] * adv[j];
                    }
#pragma unroll
                    for (int off = 1; off < 16; off <<= 1) {
                        vs += __shfl_xor(vs, off);
                        vd += __shfl_xor(vd, off);
                    }
                    int gr = row0 + wm * 64 + i * 16 + lg * 4 + rr;
                    if (l15 == 0 && gr < M) {
                        es[gr * 4 + head] = vs;
                        ed[gr * 4 + head] = vd;
                    }
                }
        } else {
            // H=1: wave covers 32 of 64 cols; cross-wave (wn) reduce via LDS
            __shared__ float esp[2][BM], edp[2][BM];
            float asv[FRN], adv[FRN];
#pragma unroll
            for (int j = 0; j < FRN; ++j) {
                asv[j] = as_[wn * (BN / 2) + j * 16 + l15];
                adv[j] = ad_[wn * (BN / 2) + j * 16 + l15];
            }
#pragma unroll
            for (int i = 0; i < 4; ++i)
#pragma unroll
                for (int rr = 0; rr < 4; ++rr) {
                    float vs = 0.f, vd = 0.f;
#pragma unroll
                    for (int j = 0; j < FRN; ++j) {
                        vs += acc[i][j][rr] * asv[j];
                        vd += acc[i][j][rr] * adv[j];
                    }
#pragma unroll
                    for (int off = 1; off < 16; off <<= 1) {
                        vs += __shfl_xor(vs, off);
                        vd += __shfl_xor(vd, off);
                    }
                    int rl = wm * 64 + i * 16 + lg * 4 + rr;
                    if (l15 == 0) { esp[wn][rl] = vs; edp[wn][rl] = vd; }
                }
            __syncthreads();
            if (tid < BM) {
                int gr = row0 + tid;
                if (gr < M) {
                    es[gr] = esp[0][tid] + esp[1][tid];
                    ed[gr] = edp[0][tid] + edp[1][tid];
                }
            }
        }
    }
}

// ---------------- FUSED softmax + aggregate + norm + bias + relu ----------------
// Phase B: simple 8x-unrolled loop + serial tail (round-6 structure, 40 VGPR —
// explicit pipelining/predication both regressed: R7 −6us/occ 38%, R11 −4us/occ 36%).
// FC=false: emit split-bf16 pair. FC=true: fused 64->10 classifier -> d_out.
template<int D, int H, bool FC>
__global__ __launch_bounds__(256) void agg_fused(const int* __restrict__ rowptr,
                                                 const int* __restrict__ csr_src,
                                                 const float* __restrict__ es,
                                                 const float* __restrict__ ed,
                                                 const float* __restrict__ h,
                                                 const float* __restrict__ b,
                                                 u16* __restrict__ Oh,
                                                 u16* __restrict__ Ol,
                                                 const float* __restrict__ fcW,
                                                 const float* __restrict__ fcb,
                                                 float* __restrict__ out) {
    const int TPN = D / 4;
    const int NPB = 256 / TPN;
    const int logH = (H == 4) ? 2 : 0;
    int tid = threadIdx.x;
    int n = blockIdx.x * NPB + tid / TPN;
    if (n >= NN) return;
    int gl = tid % TPN;
    int start = rowptr[n], end = rowptr[n + 1];

    // ---- phase A: per-head max over edges (edge-parallel) ----
    int headA = gl & (H - 1);
    const int JP = TPN >> logH;
    float edvA = ed[n * H + headA];
    float m = -1e30f;
    for (int i = start + (gl >> logH); i < end; i += JP) {
        int src = csr_src[i];
        float v = es[src * H + headA] + edvA;
        v = v > 0.f ? v : 0.2f * v;
        m = fmaxf(m, v);
    }
#pragma unroll
    for (int off = H; off < TPN; off <<= 1)
        m = fmaxf(m, __shfl_xor(m, off));

    // ---- phase B: serial edge loop, p inline, gather h ----
    int f0 = gl * 4;
    int hb = f0 >> 6;
    float mB;
    if (D == 256) mB = __shfl(m, hb);
    else          mB = m;
    float edv = ed[n * H + hb];
    float sump = 0.f;
    float4 acc = make_float4(0.f, 0.f, 0.f, 0.f);
    int i = start;
    for (; i + 8 <= end; i += 8) {
        int s0 = csr_src[i + 0], s1 = csr_src[i + 1], s2 = csr_src[i + 2], s3 = csr_src[i + 3];
        int s4 = csr_src[i + 4], s5 = csr_src[i + 5], s6 = csr_src[i + 6], s7 = csr_src[i + 7];
        float v0 = es[s0 * H + hb] + edv, v1 = es[s1 * H + hb] + edv;
        float v2 = es[s2 * H + hb] + edv, v3 = es[s3 * H + hb] + edv;
        float v4 = es[s4 * H + hb] + edv, v5 = es[s5 * H + hb] + edv;
        float v6 = es[s6 * H + hb] + edv, v7 = es[s7 * H + hb] + edv;
        v0 = v0 > 0.f ? v0 : 0.2f * v0; v1 = v1 > 0.f ? v1 : 0.2f * v1;
        v2 = v2 > 0.f ? v2 : 0.2f * v2; v3 = v3 > 0.f ? v3 : 0.2f * v3;
        v4 = v4 > 0.f ? v4 : 0.2f * v4; v5 = v5 > 0.f ? v5 : 0.2f * v5;
        v6 = v6 > 0.f ? v6 : 0.2f * v6; v7 = v7 > 0.f ? v7 : 0.2f * v7;
        float p0 = __expf(v0 - mB), p1 = __expf(v1 - mB);
        float p2 = __expf(v2 - mB), p3 = __expf(v3 - mB);
        float p4 = __expf(v4 - mB), p5 = __expf(v5 - mB);
        float p6 = __expf(v6 - mB), p7 = __expf(v7 - mB);
        float4 h0 = *reinterpret_cast<const float4*>(h + (size_t)s0 * D + f0);
        float4 h1 = *reinterpret_cast<const float4*>(h + (size_t)s1 * D + f0);
        float4 h2 = *reinterpret_cast<const float4*>(h + (size_t)s2 * D + f0);
        float4 h3 = *reinterpret_cast<const float4*>(h + (size_t)s3 * D + f0);
        float4 h4 = *reinterpret_cast<const float4*>(h + (size_t)s4 * D + f0);
        float4 h5 = *reinterpret_cast<const float4*>(h + (size_t)s5 * D + f0);
        float4 h6 = *reinterpret_cast<const float4*>(h + (size_t)s6 * D + f0);
        float4 h7 = *reinterpret_cast<const float4*>(h + (size_t)s7 * D + f0);
        acc.x += p0 * h0.x + p1 * h1.x + p2 * h2.x + p3 * h3.x
               + p4 * h4.x + p5 * h5.x + p6 * h6.x + p7 * h7.x;
        acc.y += p0 * h0.y + p1 * h1.y + p2 * h2.y + p3 * h3.y
               + p4 * h4.y + p5 * h5.y + p6 * h6.y + p7 * h7.y;
        acc.z += p0 * h0.z + p1 * h1.z + p2 * h2.z + p3 * h3.z
               + p4 * h4.z + p5 * h5.z + p6 * h6.z + p7 * h7.z;
        acc.w += p0 * h0.w + p1 * h1.w + p2 * h2.w + p3 * h3.w
               + p4 * h4.w + p5 * h5.w + p6 * h6.w + p7 * h7.w;
        sump += p0 + p1 + p2 + p3 + p4 + p5 + p6 + p7;
    }
    for (; i < end; ++i) {
        int s0 = csr_src[i];
        float v = es[s0 * H + hb] + edv;
        v = v > 0.f ? v : 0.2f * v;
        float p = __expf(v - mB);
        float4 h0 = *reinterpret_cast<const float4*>(h + (size_t)s0 * D + f0);
        acc.x += p * h0.x; acc.y += p * h0.y; acc.z += p * h0.z; acc.w += p * h0.w;
        sump += p;
    }
    float inv = 1.f / (sump + 1e-16f);
    float4 bb = *reinterpret_cast<const float4*>(b + f0);
    float4 o;
    o.x = acc.x * inv + bb.x; o.y = acc.y * inv + bb.y;
    o.z = acc.z * inv + bb.z; o.w = acc.w * inv + bb.w;
    o.x = o.x > 0.f ? o.x : 0.f; o.y = o.y > 0.f ? o.y : 0.f;
    o.z = o.z > 0.f ? o.z : 0.f; o.w = o.w > 0.f ? o.w : 0.f;
    if (!FC) {
        ushort4 hv, lv;
        hv.x = f2bf(o.x); lv.x = f2bf(o.x - bf2f(hv.x));
        hv.y = f2bf(o.y); lv.y = f2bf(o.y - bf2f(hv.y));
        hv.z = f2bf(o.z); lv.z = f2bf(o.z - bf2f(hv.z));
        hv.w = f2bf(o.w); lv.w = f2bf(o.w - bf2f(hv.w));
        *reinterpret_cast<ushort4*>(Oh + (size_t)n * D + f0) = hv;
        *reinterpret_cast<ushort4*>(Ol + (size_t)n * D + f0) = lv;
    } else {
        // fused 64->10 classifier: lane holds features f0..f0+3
        float pj[10];
#pragma unroll
        for (int j = 0; j < 10; ++j)
            pj[j] = o.x * fcW[(f0 + 0) * 10 + j] + o.y * fcW[(f0 + 1) * 10 + j]
                  + o.z * fcW[(f0 + 2) * 10 + j] + o.w * fcW[(f0 + 3) * 10 + j];
#pragma unroll
        for (int off = 1; off < 16; off <<= 1)
#pragma unroll
            for (int j = 0; j < 10; ++j)
                pj[j] += __shfl_xor(pj[j], off);
        if (gl < 10) {
            float r = 0.f;                 // static-index select (avoid scratch)
#pragma unroll
            for (int j = 0; j < 10; ++j) if (gl == j) r = pj[j];
            out[n * 10 + gl] = r + fcb[gl];
        }
    }
}

extern "C" void kernel_launch(void* const* d_in, const int* in_sizes, int n_in,
                              void* d_out, int out_size, void* d_ws, size_t ws_size,
                              hipStream_t stream) {
    const float* x   = (const float*)d_in[0];
    const int*   ei  = (const int*)d_in[1];
    const float* W1  = (const float*)d_in[2];
    const float* a1s = (const float*)d_in[3];
    const float* a1d = (const float*)d_in[4];
    const float* b1  = (const float*)d_in[5];
    const float* W2  = (const float*)d_in[6];
    const float* a2s = (const float*)d_in[7];
    const float* a2d = (const float*)d_in[8];
    const float* b2  = (const float*)d_in[9];
    const float* W3  = (const float*)d_in[10];
    const float* a3s = (const float*)d_in[11];
    const float* a3d = (const float*)d_in[12];
    const float* b3  = (const float*)d_in[13];
    const float* fcW = (const float*)d_in[14];
    const float* fcb = (const float*)d_in[15];
    float* out = (float*)d_out;

    // ---- workspace layout ----
    char* wp = (char*)d_ws;
    float* h   = (float*)wp;  wp += (size_t)NN * 256 * 4;     // GEMM output, f32
    u16* Ph    = (u16*)wp;    wp += (size_t)NN * 256 * 2;     // activation hi
    u16* Pl    = (u16*)wp;    wp += (size_t)NN * 256 * 2;     // activation lo
    u16* Xh    = (u16*)wp;    wp += (size_t)NN * 128 * 2;     // x hi
    u16* Xl    = (u16*)wp;    wp += (size_t)NN * 128 * 2;     // x lo
    float* ES  = (float*)wp;  wp += (size_t)NN * 4 * 4;
    float* ED  = (float*)wp;  wp += (size_t)NN * 4 * 4;
    u16* Wth   = (u16*)wp;    wp += 256 * 256 * 2;
    u16* Wtl   = (u16*)wp;    wp += 256 * 256 * 2;
    int* rowptr = (int*)wp;   wp += (NN + 1) * 4;
    int* csrsrc = (int*)wp;   wp += (size_t)E2 * 4;
    int* deg    = (int*)wp;   wp += NN * 4;
    int* bsum   = (int*)wp;   wp += 256 * 4;
    int* boff   = (int*)wp;   wp += 256 * 4;
    int* cursor = (int*)((char*)d_ws + (size_t)NN * 256 * 4);  // alias Ph (pre-layer only)

    // ---- build CSR ----
    fill_i32<<<(NN + 255) / 256, 256, 0, stream>>>(deg, 1, NN);
    hist_dst<<<(NE + 255) / 256, 256, 0, stream>>>(ei, deg);
    block_sums<<<SCAN_B, 256, 0, stream>>>(deg, bsum);
    scan_bsums<<<1, 256, 0, stream>>>(bsum, boff);
    scan_final<<<SCAN_B, 256, 0, stream>>>(deg, boff, rowptr, cursor);
    scatter_csr<<<(E2 + 255) / 256, 256, 0, stream>>>(ei, cursor, csrsrc);

    // ---- split input x ----
    xconv<<<(NN * IN_DIM / 4 + 255) / 256, 256, 0, stream>>>(x, Xh, Xl, NN * IN_DIM / 4);

    const int MT = (NN + 127) / 128;

    // ======== layer 1: K=128, D=256, H=4 (escore fused into GEMM) ========
    wconv<<<(IN_DIM * 256 + 255) / 256, 256, 0, stream>>>(W1, Wth, Wtl, IN_DIM, 256);
    gemm_mfma<128, 128, true><<<dim3(MT, 2), 256, 0, stream>>>(Xh, Xl, Wth, Wtl, h, NN, 256,
                                                               a1s, a1d, ES, ED);
    agg_fused<256, 4, false><<<(NN + 3) / 4, 256, 0, stream>>>(rowptr, csrsrc, ES, ED, h, b1,
                                                               Ph, Pl, nullptr, nullptr, nullptr);

    // ======== layer 2: K=256, D=256, H=4 (escore fused into GEMM) ========
    wconv<<<(256 * 256 + 255) / 256, 256, 0, stream>>>(W2, Wth, Wtl, 256, 256);
    gemm_mfma<128, 256, true><<<dim3(MT, 2), 256, 0, stream>>>(Ph, Pl, Wth, Wtl, h, NN, 256,
                                                               a2s, a2d, ES, ED);
    agg_fused<256, 4, false><<<(NN + 3) / 4, 256, 0, stream>>>(rowptr, csrsrc, ES, ED, h, b2,
                                                               Ph, Pl, nullptr, nullptr, nullptr);

    // ======== layer 3: K=256, D=64, H=1 (escore fused into GEMM, fc fused into agg) ========
    wconv<<<(256 * 64 + 255) / 256, 256, 0, stream>>>(W3, Wth, Wtl, 256, 64);
    gemm_mfma<64, 256, true><<<dim3(MT, 1), 256, 0, stream>>>(Ph, Pl, Wth, Wtl, h, NN, 64,
                                                              a3s, a3d, ES, ED);
    agg_fused<64, 1, true><<<(NN + 15) / 16, 256, 0, stream>>>(rowptr, csrsrc, ES, ED, h, b3,
                                                               nullptr, nullptr, fcW, fcb, out);
}

// Round 15
// 519.344 us; speedup vs baseline: 1.0515x; 1.0030x over previous
//
#include <hip/hip_runtime.h>

#define NN 50000
#define NE 800000
#define E2 (NE + NN)   // edges + self loops
#define IN_DIM 128
#define SCAN_B 196     // ceil(NN/256)

typedef unsigned short u16;
typedef unsigned int u32;
typedef __attribute__((ext_vector_type(8))) short short8;
typedef __attribute__((ext_vector_type(4))) float f32x4;

__device__ inline u16 f2bf(float x) {
    u32 u = __float_as_uint(x);
    u32 r = (u + 0x7fff + ((u >> 16) & 1)) >> 16;   // RNE
    return (u16)r;
}
__device__ inline float bf2f(u16 h) { return __uint_as_float(((u32)h) << 16); }

// ---------------- CSR build ----------------
__global__ __launch_bounds__(256) void hist_dst(const int* __restrict__ ei, int* __restrict__ deg) {
    int e = blockIdx.x * 256 + threadIdx.x;
    if (e < NE) atomicAdd(&deg[ei[NE + e]], 1);
}

// per-256-chunk sums of (deg+1)
__global__ __launch_bounds__(256) void block_sums(const int* __restrict__ deg, int* __restrict__ bsum) {
    int b = blockIdx.x;
    int i = b * 256 + threadIdx.x;
    int v = (i < NN) ? deg[i] + 1 : 0;   // +1 self-loop
#pragma unroll
    for (int off = 32; off; off >>= 1) v += __shfl_down(v, off);
    __shared__ int ws[4];
    if ((threadIdx.x & 63) == 0) ws[threadIdx.x >> 6] = v;
    __syncthreads();
    if (threadIdx.x == 0) bsum[b] = ws[0] + ws[1] + ws[2] + ws[3];
}

// fused: each block scans the 196 bsums in LDS (redundantly) + local scan -> rowptr/cursor
__global__ __launch_bounds__(256) void scan_final(const int* __restrict__ deg,
                                                  const int* __restrict__ bsum,
                                                  int* __restrict__ rowptr,
                                                  int* __restrict__ cursor) {
    __shared__ int sb[256];
    int b = blockIdx.x;
    int t = threadIdx.x;
    int v0 = (t < SCAN_B) ? bsum[t] : 0;
    sb[t] = v0;
    __syncthreads();
    for (int off = 1; off < 256; off <<= 1) {
        int u = (t >= off) ? sb[t - off] : 0;
        __syncthreads();
        sb[t] += u;
        __syncthreads();
    }
    int boff = (b == 0) ? 0 : sb[b - 1];
    __syncthreads();   // sb reuse
    int i = b * 256 + t;
    int v = (i < NN) ? deg[i] + 1 : 0;   // +1 self-loop
    sb[t] = v;
    __syncthreads();
    for (int off = 1; off < 256; off <<= 1) {
        int u = (t >= off) ? sb[t - off] : 0;
        __syncthreads();
        sb[t] += u;
        __syncthreads();
    }
    int excl = sb[t] - v + boff;
    if (i < NN) { rowptr[i] = excl; cursor[i] = excl; }
    if (i == NN - 1) rowptr[NN] = excl + v;
}

__global__ __launch_bounds__(256) void scatter_csr(const int* __restrict__ ei,
                                                   int* __restrict__ cursor,
                                                   int* __restrict__ csr_src) {
    int e = blockIdx.x * 256 + threadIdx.x;
    if (e >= E2) return;
    int s, d;
    if (e < NE) { s = ei[e]; d = ei[NE + e]; } else { s = d = e - NE; }
    int pos = atomicAdd(&cursor[d], 1);
    csr_src[pos] = s;
}

// ---------------- split-bf16 converters ----------------
__global__ __launch_bounds__(256) void xconv(const float* __restrict__ X,
                                             u16* __restrict__ Xh, u16* __restrict__ Xl,
                                             int total4) {
    int i = blockIdx.x * 256 + threadIdx.x;
    if (i >= total4) return;
    float4 v = reinterpret_cast<const float4*>(X)[i];
    ushort4 h, l;
    h.x = f2bf(v.x); l.x = f2bf(v.x - bf2f(h.x));
    h.y = f2bf(v.y); l.y = f2bf(v.y - bf2f(h.y));
    h.z = f2bf(v.z); l.z = f2bf(v.z - bf2f(h.z));
    h.w = f2bf(v.w); l.w = f2bf(v.w - bf2f(h.w));
    reinterpret_cast<ushort4*>(Xh)[i] = h;
    reinterpret_cast<ushort4*>(Xl)[i] = l;
}

// all three weight matrices transposed+split in ONE launch (outputs [N][K])
__global__ __launch_bounds__(256) void wconv_all(const float* __restrict__ W1,
                                                 const float* __restrict__ W2,
                                                 const float* __restrict__ W3,
                                                 u16* __restrict__ W1h, u16* __restrict__ W1l,
                                                 u16* __restrict__ W2h, u16* __restrict__ W2l,
                                                 u16* __restrict__ W3h, u16* __restrict__ W3l) {
    int idx = blockIdx.x * 256 + threadIdx.x;
    if (idx < 32768) {                       // W1: 128x256
        int k = idx >> 8, n = idx & 255;
        float w = W1[idx];
        u16 hi = f2bf(w);
        W1h[n * 128 + k] = hi;
        W1l[n * 128 + k] = f2bf(w - bf2f(hi));
    } else if (idx < 32768 + 65536) {        // W2: 256x256
        int j = idx - 32768;
        int k = j >> 8, n = j & 255;
        float w = W2[j];
        u16 hi = f2bf(w);
        W2h[n * 256 + k] = hi;
        W2l[n * 256 + k] = f2bf(w - bf2f(hi));
    } else if (idx < 114688) {               // W3: 256x64
        int j = idx - 98304;
        int k = j >> 6, n = j & 63;
        float w = W3[j];
        u16 hi = f2bf(w);
        W3h[n * 256 + k] = hi;
        W3l[n * 256 + k] = f2bf(w - bf2f(hi));
    }
}

// ---------------- split-bf16 MFMA GEMM (double-buffered A, 1 barrier/K-step) ----------------
// R12 structure (local optimum: R8 LDS-heavier flat, R13 LDS-free −13.5us).
// A staged via 2x LDS buffers w/ 2-step register prefetch; B direct from global (L2-hot).
// FES epilogue: BN=128 (H=4) wave owns one head; BN=64 (H=1) cross-wave LDS reduce.
template<int BN, int KK, bool FES>
__global__ __launch_bounds__(256) void gemm_mfma(const u16* __restrict__ Ah,
                                                 const u16* __restrict__ Al,
                                                 const u16* __restrict__ Wh,
                                                 const u16* __restrict__ Wl,
                                                 float* __restrict__ C,
                                                 int M, int N,
                                                 const float* __restrict__ as_,
                                                 const float* __restrict__ ad_,
                                                 float* __restrict__ es,
                                                 float* __restrict__ ed) {
    const int BM = 128, BK = 32, LDT = BK + 8;
    __shared__ u16 Ahs[2][BM][LDT], Als[2][BM][LDT];   // 40 KB
    const int FRN = BN / 32;
    int tid = threadIdx.x;
    int lane = tid & 63, wid = tid >> 6;
    int wm = wid >> 1, wn = wid & 1;
    int row0 = blockIdx.x * BM, col0 = blockIdx.y * BN;
    int l15 = lane & 15, lg = lane >> 4;

    int c0 = tid * 2;
    int r_a = c0 >> 2, sub_a0 = (c0 & 3) * 8, sub_a1 = ((c0 + 1) & 3) * 8;
    int gr_a = row0 + r_a;

    uint4 avh[2], avl[2];
    auto loadA = [&](int ko) {
        if (gr_a < M) {
            avh[0] = *reinterpret_cast<const uint4*>(Ah + (size_t)gr_a * KK + ko + sub_a0);
            avl[0] = *reinterpret_cast<const uint4*>(Al + (size_t)gr_a * KK + ko + sub_a0);
            avh[1] = *reinterpret_cast<const uint4*>(Ah + (size_t)gr_a * KK + ko + sub_a1);
            avl[1] = *reinterpret_cast<const uint4*>(Al + (size_t)gr_a * KK + ko + sub_a1);
        } else {
            avh[0] = avh[1] = avl[0] = avl[1] = make_uint4(0, 0, 0, 0);
        }
    };
    auto writeA = [&](int p) {
        *reinterpret_cast<uint4*>(&Ahs[p][r_a][sub_a0]) = avh[0];
        *reinterpret_cast<uint4*>(&Als[p][r_a][sub_a0]) = avl[0];
        *reinterpret_cast<uint4*>(&Ahs[p][r_a][sub_a1]) = avh[1];
        *reinterpret_cast<uint4*>(&Als[p][r_a][sub_a1]) = avl[1];
    };

    f32x4 acc[4][FRN];
#pragma unroll
    for (int i = 0; i < 4; ++i)
#pragma unroll
        for (int j = 0; j < FRN; ++j) acc[i][j] = (f32x4){0.f, 0.f, 0.f, 0.f};

    loadA(0);
    writeA(0);
    loadA(BK);
    __syncthreads();

    for (int ko = 0; ko < KK; ko += BK) {
        int p = (ko >> 5) & 1;
        if (ko + BK < KK) {
            writeA(p ^ 1);
            if (ko + 2 * BK < KK) loadA(ko + 2 * BK);
        }
        short8 bh[FRN], bl[FRN];
#pragma unroll
        for (int j = 0; j < FRN; ++j) {
            int gc = col0 + wn * (BN / 2) + j * 16 + l15;
            bh[j] = *reinterpret_cast<const short8*>(Wh + (size_t)gc * KK + ko + lg * 8);
            bl[j] = *reinterpret_cast<const short8*>(Wl + (size_t)gc * KK + ko + lg * 8);
        }
        short8 ah[4], al[4];
#pragma unroll
        for (int i = 0; i < 4; ++i) {
            int r = wm * 64 + i * 16 + l15;
            ah[i] = *reinterpret_cast<const short8*>(&Ahs[p][r][lg * 8]);
            al[i] = *reinterpret_cast<const short8*>(&Als[p][r][lg * 8]);
        }
#pragma unroll
        for (int i = 0; i < 4; ++i)
#pragma unroll
            for (int j = 0; j < FRN; ++j) {
                acc[i][j] = __builtin_amdgcn_mfma_f32_16x16x32_bf16(ah[i], bh[j], acc[i][j], 0, 0, 0);
                acc[i][j] = __builtin_amdgcn_mfma_f32_16x16x32_bf16(ah[i], bl[j], acc[i][j], 0, 0, 0);
                acc[i][j] = __builtin_amdgcn_mfma_f32_16x16x32_bf16(al[i], bh[j], acc[i][j], 0, 0, 0);
            }
        __syncthreads();
    }
    // C store
#pragma unroll
    for (int i = 0; i < 4; ++i)
#pragma unroll
        for (int rr = 0; rr < 4; ++rr) {
            int gr = row0 + wm * 64 + i * 16 + lg * 4 + rr;
            if (gr < M) {
#pragma unroll
                for (int j = 0; j < FRN; ++j)
                    C[(size_t)gr * N + col0 + wn * (BN / 2) + j * 16 + l15] = acc[i][j][rr];
            }
        }
    if (FES) {
        if constexpr (BN == 128) {
            int head = (col0 + wn * (BN / 2)) >> 6;
            float asv[FRN], adv[FRN];
#pragma unroll
            for (int j = 0; j < FRN; ++j) {
                asv[j] = as_[head * 64 + j * 16 + l15];
                adv[j] = ad_[head * 64 + j * 16 + l15];
            }
#pragma unroll
            for (int i = 0; i < 4; ++i)
#pragma unroll
                for (int rr = 0; rr < 4; ++rr) {
                    float vs = 0.f, vd = 0.f;
#pragma unroll
                    for (int j = 0; j < FRN; ++j) {
                        vs += acc[i][j][rr] * asv[j];
                        vd += acc[i][j][rr] * adv[j];
                    }
#pragma unroll
                    for (int off = 1; off < 16; off <<= 1) {
                        vs += __shfl_xor(vs, off);
                        vd += __shfl_xor(vd, off);
                    }
                    int gr = row0 + wm * 64 + i * 16 + lg * 4 + rr;
                    if (l15 == 0 && gr < M) {
                        es[gr * 4 + head] = vs;
                        ed[gr * 4 + head] = vd;
                    }
                }
        } else {
            // H=1: wave covers 32 of 64 cols; cross-wave (wn) reduce via LDS
            __shared__ float esp[2][BM], edp[2][BM];
            float asv[FRN], adv[FRN];
#pragma unroll
            for (int j = 0; j < FRN; ++j) {
                asv[j] = as_[wn * (BN / 2) + j * 16 + l15];
                adv[j] = ad_[wn * (BN / 2) + j * 16 + l15];
            }
#pragma unroll
            for (int i = 0; i < 4; ++i)
#pragma unroll
                for (int rr = 0; rr < 4; ++rr) {
                    float vs = 0.f, vd = 0.f;
#pragma unroll
                    for (int j = 0; j < FRN; ++j) {
                        vs += acc[i][j][rr] * asv[j];
                        vd += acc[i][j][rr] * adv[j];
                    }
#pragma unroll
                    for (int off = 1; off < 16; off <<= 1) {
                        vs += __shfl_xor(vs, off);
                        vd += __shfl_xor(vd, off);
                    }
                    int rl = wm * 64 + i * 16 + lg * 4 + rr;
                    if (l15 == 0) { esp[wn][rl] = vs; edp[wn][rl] = vd; }
                }
            __syncthreads();
            if (tid < BM) {
                int gr = row0 + tid;
                if (gr < M) {
                    es[gr] = esp[0][tid] + esp[1][tid];
                    ed[gr] = edp[0][tid] + edp[1][tid];
                }
            }
        }
    }
}

// ---------------- FUSED softmax + aggregate + norm + bias + relu ----------------
// Phase B: simple 8x-unrolled loop + serial tail (round-6 structure, 40 VGPR —
// explicit pipelining/predication both regressed: R7 −6us/occ 38%, R11 −4us/occ 36%).
// FC=false: emit split-bf16 pair. FC=true: fused 64->10 classifier -> d_out.
template<int D, int H, bool FC>
__global__ __launch_bounds__(256) void agg_fused(const int* __restrict__ rowptr,
                                                 const int* __restrict__ csr_src,
                                                 const float* __restrict__ es,
                                                 const float* __restrict__ ed,
                                                 const float* __restrict__ h,
                                                 const float* __restrict__ b,
                                                 u16* __restrict__ Oh,
                                                 u16* __restrict__ Ol,
                                                 const float* __restrict__ fcW,
                                                 const float* __restrict__ fcb,
                                                 float* __restrict__ out) {
    const int TPN = D / 4;
    const int NPB = 256 / TPN;
    const int logH = (H == 4) ? 2 : 0;
    int tid = threadIdx.x;
    int n = blockIdx.x * NPB + tid / TPN;
    if (n >= NN) return;
    int gl = tid % TPN;
    int start = rowptr[n], end = rowptr[n + 1];

    // ---- phase A: per-head max over edges (edge-parallel) ----
    int headA = gl & (H - 1);
    const int JP = TPN >> logH;
    float edvA = ed[n * H + headA];
    float m = -1e30f;
    for (int i = start + (gl >> logH); i < end; i += JP) {
        int src = csr_src[i];
        float v = es[src * H + headA] + edvA;
        v = v > 0.f ? v : 0.2f * v;
        m = fmaxf(m, v);
    }
#pragma unroll
    for (int off = H; off < TPN; off <<= 1)
        m = fmaxf(m, __shfl_xor(m, off));

    // ---- phase B: serial edge loop, p inline, gather h ----
    int f0 = gl * 4;
    int hb = f0 >> 6;
    float mB;
    if (D == 256) mB = __shfl(m, hb);
    else          mB = m;
    float edv = ed[n * H + hb];
    float sump = 0.f;
    float4 acc = make_float4(0.f, 0.f, 0.f, 0.f);
    int i = start;
    for (; i + 8 <= end; i += 8) {
        int s0 = csr_src[i + 0], s1 = csr_src[i + 1], s2 = csr_src[i + 2], s3 = csr_src[i + 3];
        int s4 = csr_src[i + 4], s5 = csr_src[i + 5], s6 = csr_src[i + 6], s7 = csr_src[i + 7];
        float v0 = es[s0 * H + hb] + edv, v1 = es[s1 * H + hb] + edv;
        float v2 = es[s2 * H + hb] + edv, v3 = es[s3 * H + hb] + edv;
        float v4 = es[s4 * H + hb] + edv, v5 = es[s5 * H + hb] + edv;
        float v6 = es[s6 * H + hb] + edv, v7 = es[s7 * H + hb] + edv;
        v0 = v0 > 0.f ? v0 : 0.2f * v0; v1 = v1 > 0.f ? v1 : 0.2f * v1;
        v2 = v2 > 0.f ? v2 : 0.2f * v2; v3 = v3 > 0.f ? v3 : 0.2f * v3;
        v4 = v4 > 0.f ? v4 : 0.2f * v4; v5 = v5 > 0.f ? v5 : 0.2f * v5;
        v6 = v6 > 0.f ? v6 : 0.2f * v6; v7 = v7 > 0.f ? v7 : 0.2f * v7;
        float p0 = __expf(v0 - mB), p1 = __expf(v1 - mB);
        float p2 = __expf(v2 - mB), p3 = __expf(v3 - mB);
        float p4 = __expf(v4 - mB), p5 = __expf(v5 - mB);
        float p6 = __expf(v6 - mB), p7 = __expf(v7 - mB);
        float4 h0 = *reinterpret_cast<const float4*>(h + (size_t)s0 * D + f0);
        float4 h1 = *reinterpret_cast<const float4*>(h + (size_t)s1 * D + f0);
        float4 h2 = *reinterpret_cast<const float4*>(h + (size_t)s2 * D + f0);
        float4 h3 = *reinterpret_cast<const float4*>(h + (size_t)s3 * D + f0);
        float4 h4 = *reinterpret_cast<const float4*>(h + (size_t)s4 * D + f0);
        float4 h5 = *reinterpret_cast<const float4*>(h + (size_t)s5 * D + f0);
        float4 h6 = *reinterpret_cast<const float4*>(h + (size_t)s6 * D + f0);
        float4 h7 = *reinterpret_cast<const float4*>(h + (size_t)s7 * D + f0);
        acc.x += p0 * h0.x + p1 * h1.x + p2 * h2.x + p3 * h3.x
               + p4 * h4.x + p5 * h5.x + p6 * h6.x + p7 * h7.x;
        acc.y += p0 * h0.y + p1 * h1.y + p2 * h2.y + p3 * h3.y
               + p4 * h4.y + p5 * h5.y + p6 * h6.y + p7 * h7.y;
        acc.z += p0 * h0.z + p1 * h1.z + p2 * h2.z + p3 * h3.z
               + p4 * h4.z + p5 * h5.z + p6 * h6.z + p7 * h7.z;
        acc.w += p0 * h0.w + p1 * h1.w + p2 * h2.w + p3 * h3.w
               + p4 * h4.w + p5 * h5.w + p6 * h6.w + p7 * h7.w;
        sump += p0 + p1 + p2 + p3 + p4 + p5 + p6 + p7;
    }
    for (; i < end; ++i) {
        int s0 = csr_src[i];
        float v = es[s0 * H + hb] + edv;
        v = v > 0.f ? v : 0.2f * v;
        float p = __expf(v - mB);
        float4 h0 = *reinterpret_cast<const float4*>(h + (size_t)s0 * D + f0);
        acc.x += p * h0.x; acc.y += p * h0.y; acc.z += p * h0.z; acc.w += p * h0.w;
        sump += p;
    }
    float inv = 1.f / (sump + 1e-16f);
    float4 bb = *reinterpret_cast<const float4*>(b + f0);
    float4 o;
    o.x = acc.x * inv + bb.x; o.y = acc.y * inv + bb.y;
    o.z = acc.z * inv + bb.z; o.w = acc.w * inv + bb.w;
    o.x = o.x > 0.f ? o.x : 0.f; o.y = o.y > 0.f ? o.y : 0.f;
    o.z = o.z > 0.f ? o.z : 0.f; o.w = o.w > 0.f ? o.w : 0.f;
    if (!FC) {
        ushort4 hv, lv;
        hv.x = f2bf(o.x); lv.x = f2bf(o.x - bf2f(hv.x));
        hv.y = f2bf(o.y); lv.y = f2bf(o.y - bf2f(hv.y));
        hv.z = f2bf(o.z); lv.z = f2bf(o.z - bf2f(hv.z));
        hv.w = f2bf(o.w); lv.w = f2bf(o.w - bf2f(hv.w));
        *reinterpret_cast<ushort4*>(Oh + (size_t)n * D + f0) = hv;
        *reinterpret_cast<ushort4*>(Ol + (size_t)n * D + f0) = lv;
    } else {
        // fused 64->10 classifier: lane holds features f0..f0+3
        float pj[10];
#pragma unroll
        for (int j = 0; j < 10; ++j)
            pj[j] = o.x * fcW[(f0 + 0) * 10 + j] + o.y * fcW[(f0 + 1) * 10 + j]
                  + o.z * fcW[(f0 + 2) * 10 + j] + o.w * fcW[(f0 + 3) * 10 + j];
#pragma unroll
        for (int off = 1; off < 16; off <<= 1)
#pragma unroll
            for (int j = 0; j < 10; ++j)
                pj[j] += __shfl_xor(pj[j], off);
        if (gl < 10) {
            float r = 0.f;                 // static-index select (avoid scratch)
#pragma unroll
            for (int j = 0; j < 10; ++j) if (gl == j) r = pj[j];
            out[n * 10 + gl] = r + fcb[gl];
        }
    }
}

extern "C" void kernel_launch(void* const* d_in, const int* in_sizes, int n_in,
                              void* d_out, int out_size, void* d_ws, size_t ws_size,
                              hipStream_t stream) {
    const float* x   = (const float*)d_in[0];
    const int*   ei  = (const int*)d_in[1];
    const float* W1  = (const float*)d_in[2];
    const float* a1s = (const float*)d_in[3];
    const float* a1d = (const float*)d_in[4];
    const float* b1  = (const float*)d_in[5];
    const float* W2  = (const float*)d_in[6];
    const float* a2s = (const float*)d_in[7];
    const float* a2d = (const float*)d_in[8];
    const float* b2  = (const float*)d_in[9];
    const float* W3  = (const float*)d_in[10];
    const float* a3s = (const float*)d_in[11];
    const float* a3d = (const float*)d_in[12];
    const float* b3  = (const float*)d_in[13];
    const float* fcW = (const float*)d_in[14];
    const float* fcb = (const float*)d_in[15];
    float* out = (float*)d_out;

    // ---- workspace layout ----
    char* wp = (char*)d_ws;
    float* h   = (float*)wp;  wp += (size_t)NN * 256 * 4;     // GEMM output, f32
    u16* Ph    = (u16*)wp;    wp += (size_t)NN * 256 * 2;     // activation hi
    u16* Pl    = (u16*)wp;    wp += (size_t)NN * 256 * 2;     // activation lo
    u16* Xh    = (u16*)wp;    wp += (size_t)NN * 128 * 2;     // x hi
    u16* Xl    = (u16*)wp;    wp += (size_t)NN * 128 * 2;     // x lo
    float* ES  = (float*)wp;  wp += (size_t)NN * 4 * 4;
    float* ED  = (float*)wp;  wp += (size_t)NN * 4 * 4;
    u16* W1h   = (u16*)wp;    wp += 128 * 256 * 2;
    u16* W1l   = (u16*)wp;    wp += 128 * 256 * 2;
    u16* W2h   = (u16*)wp;    wp += 256 * 256 * 2;
    u16* W2l   = (u16*)wp;    wp += 256 * 256 * 2;
    u16* W3h   = (u16*)wp;    wp += 256 * 64 * 2;
    u16* W3l   = (u16*)wp;    wp += 256 * 64 * 2;
    int* rowptr = (int*)wp;   wp += (NN + 1) * 4;
    int* csrsrc = (int*)wp;   wp += (size_t)E2 * 4;
    int* deg    = (int*)wp;   wp += NN * 4;
    int* bsum   = (int*)wp;   wp += 256 * 4;
    int* cursor = (int*)((char*)d_ws + (size_t)NN * 256 * 4);  // alias Ph (pre-layer only)

    // ---- build CSR (deg memset to 0; +1 self-loop folded into scan readers) ----
    hipMemsetAsync(deg, 0, NN * sizeof(int), stream);
    hist_dst<<<(NE + 255) / 256, 256, 0, stream>>>(ei, deg);
    block_sums<<<SCAN_B, 256, 0, stream>>>(deg, bsum);
    scan_final<<<SCAN_B, 256, 0, stream>>>(deg, bsum, rowptr, cursor);
    scatter_csr<<<(E2 + 255) / 256, 256, 0, stream>>>(ei, cursor, csrsrc);

    // ---- convert inputs: x split + ALL weights transposed/split (one launch each) ----
    xconv<<<(NN * IN_DIM / 4 + 255) / 256, 256, 0, stream>>>(x, Xh, Xl, NN * IN_DIM / 4);
    wconv_all<<<(114688 + 255) / 256, 256, 0, stream>>>(W1, W2, W3, W1h, W1l, W2h, W2l, W3h, W3l);

    const int MT = (NN + 127) / 128;

    // ======== layer 1: K=128, D=256, H=4 (escore fused into GEMM) ========
    gemm_mfma<128, 128, true><<<dim3(MT, 2), 256, 0, stream>>>(Xh, Xl, W1h, W1l, h, NN, 256,
                                                               a1s, a1d, ES, ED);
    agg_fused<256, 4, false><<<(NN + 3) / 4, 256, 0, stream>>>(rowptr, csrsrc, ES, ED, h, b1,
                                                               Ph, Pl, nullptr, nullptr, nullptr);

    // ======== layer 2: K=256, D=256, H=4 (escore fused into GEMM) ========
    gemm_mfma<128, 256, true><<<dim3(MT, 2), 256, 0, stream>>>(Ph, Pl, W2h, W2l, h, NN, 256,
                                                               a2s, a2d, ES, ED);
    agg_fused<256, 4, false><<<(NN + 3) / 4, 256, 0, stream>>>(rowptr, csrsrc, ES, ED, h, b2,
                                                               Ph, Pl, nullptr, nullptr, nullptr);

    // ======== layer 3: K=256, D=64, H=1 (escore fused into GEMM, fc fused into agg) ========
    gemm_mfma<64, 256, true><<<dim3(MT, 1), 256, 0, stream>>>(Ph, Pl, W3h, W3l, h, NN, 64,
                                                              a3s, a3d, ES, ED);
    agg_fused<64, 1, true><<<(NN + 15) / 16, 256, 0, stream>>>(rowptr, csrsrc, ES, ED, h, b3,
                                                               nullptr, nullptr, fcW, fcb, out);
}